// Round 1
// baseline (15.161 us; speedup 1.0000x reference)
//
#include <hip/hip_runtime.h>
#include <math.h>

// QueueMemory: the reference's compat() is bounded above by 0 (0.5 - hard_sigmoid(norm)
// with norm >= 0 => hard_sigmoid >= 0.5), and EPS = 0.51 > 0, so cond_q and cond_s are
// ALWAYS False. The computation mathematically reduces to:
//   r      = argmin(index)                      (first occurrence)
//   m      = argmax(index over j != r)          (first occurrence)
//   reward = sum_t states_seq[0, t, F-1]
//   if reward > index[m]:  out = (states_seq[0, T-1, :], reward)
//   else:                  out = (memory[0, m, :],       index[m])
// Output: 512 floats (mem_out) + 1 float (idx_out) = 513 fp32.

namespace {
constexpr int kT = 128;
constexpr int kF = 512;
constexpr int kMemLen = 65536;
constexpr int kThreads = 1024;
}

__global__ __launch_bounds__(kThreads)
void queue_memory_kernel(const float* __restrict__ states_seq,  // (1, 128, 512)
                         const float* __restrict__ memory,      // (1, 65536, 512)
                         const float* __restrict__ index,       // (1, 65536, 1)
                         float* __restrict__ out) {              // 513 floats
    __shared__ float s_val[kThreads];
    __shared__ int   s_idx[kThreads];
    __shared__ float s_red[kT];
    __shared__ int   s_r;
    __shared__ int   s_m;
    __shared__ float s_maxv;
    __shared__ float s_reward;

    const int tid = threadIdx.x;

    // Stage the reward column (stride-F loads) early.
    if (tid < kT) s_red[tid] = states_seq[tid * kF + (kF - 1)];

    const float4* idx4 = reinterpret_cast<const float4*>(index);

    // ---- Phase A: argmin over index (first occurrence) ----
    float mnv = INFINITY;
    int   mni = kMemLen;
    for (int j = tid; j < kMemLen / 4; j += kThreads) {
        float4 v = idx4[j];
        int b = 4 * j;
        if (v.x < mnv) { mnv = v.x; mni = b;     }
        if (v.y < mnv) { mnv = v.y; mni = b + 1; }
        if (v.z < mnv) { mnv = v.z; mni = b + 2; }
        if (v.w < mnv) { mnv = v.w; mni = b + 3; }
    }
    s_val[tid] = mnv;
    s_idx[tid] = mni;
    __syncthreads();
    for (int s = kThreads / 2; s > 0; s >>= 1) {
        if (tid < s) {
            float ov = s_val[tid + s];
            int   oi = s_idx[tid + s];
            if (ov < s_val[tid] || (ov == s_val[tid] && oi < s_idx[tid])) {
                s_val[tid] = ov;
                s_idx[tid] = oi;
            }
        }
        __syncthreads();
    }
    if (tid == 0) s_r = s_idx[0];
    __syncthreads();
    const int r = s_r;

    // ---- Phase B: argmax over index excluding r (first occurrence) ----
    // Re-reads 256 KB; resident in L2 after phase A.
    float mxv = -INFINITY;
    int   mxi = kMemLen;
    for (int j = tid; j < kMemLen / 4; j += kThreads) {
        float4 v = idx4[j];
        int b = 4 * j;
        if (b     != r && v.x > mxv) { mxv = v.x; mxi = b;     }
        if (b + 1 != r && v.y > mxv) { mxv = v.y; mxi = b + 1; }
        if (b + 2 != r && v.z > mxv) { mxv = v.z; mxi = b + 2; }
        if (b + 3 != r && v.w > mxv) { mxv = v.w; mxi = b + 3; }
    }
    s_val[tid] = mxv;
    s_idx[tid] = mxi;
    __syncthreads();
    for (int s = kThreads / 2; s > 0; s >>= 1) {
        if (tid < s) {
            float ov = s_val[tid + s];
            int   oi = s_idx[tid + s];
            if (ov > s_val[tid] || (ov == s_val[tid] && oi < s_idx[tid])) {
                s_val[tid] = ov;
                s_idx[tid] = oi;
            }
        }
        __syncthreads();
    }
    if (tid == 0) {
        s_m    = s_idx[0];
        s_maxv = s_val[0];
        float acc = 0.0f;
        for (int t = 0; t < kT; ++t) acc += s_red[t];
        s_reward = acc;
    }
    __syncthreads();

    // ---- Select + write output (branch is uniform across the block) ----
    const float reward = s_reward;
    const float maxv   = s_maxv;
    const float* src;
    float idxval;
    if (reward > maxv) {
        // Appended element (position MEM_LEN-1 of idx2) wins only on strict >.
        src    = states_seq + (size_t)(kT - 1) * kF;
        idxval = reward;
    } else {
        src    = memory + (size_t)s_m * kF;
        idxval = maxv;  // == index[m]
    }
    const float4* src4 = reinterpret_cast<const float4*>(src);
    float4*       out4 = reinterpret_cast<float4*>(out);
    for (int j = tid; j < kF / 4; j += kThreads) out4[j] = src4[j];
    if (tid == 0) out[kF] = idxval;
}

extern "C" void kernel_launch(void* const* d_in, const int* in_sizes, int n_in,
                              void* d_out, int out_size, void* d_ws, size_t ws_size,
                              hipStream_t stream) {
    const float* states_seq = (const float*)d_in[0];
    // d_in[1] = maximum_route: provably unused (cond_s always False).
    const float* memory = (const float*)d_in[2];
    const float* index  = (const float*)d_in[3];
    float* out = (float*)d_out;

    queue_memory_kernel<<<1, kThreads, 0, stream>>>(states_seq, memory, index, out);
}

// Round 2
// 12.271 us; speedup vs baseline: 1.2355x; 1.2355x over previous
//
#include <hip/hip_runtime.h>
#include <math.h>

// QueueMemory: compat() <= 0 always (0.5 - hard_sigmoid(norm>=0)), EPS=0.51 > 0,
// so cond_q/cond_s are provably False. Reduces to:
//   r      = argmin(index)                    (first occurrence)
//   m      = argmax(index over j != r)        (first occurrence)
//   reward = sum_t states_seq[0, t, F-1]
//   out = reward > index[m] ? (states_seq[0,T-1,:], reward) : (memory[0,m,:], index[m])
// Key fusion: global argmin-first and argmax-first share an index only when the
// array is constant; so m = mxi unless mxi==mni (all-equal), then m = (r==0?1:0).
// One pass over index, split across 64 blocks; tiny finalize kernel.

namespace {
constexpr int kT       = 128;
constexpr int kF       = 512;
constexpr int kMemLen  = 65536;
constexpr int kBlocks1 = 64;
constexpr int kThr     = 256;   // 64 blk * 256 thr * 4 elems = 65536
}

struct MinMax { float mnv; int mni; float mxv; int mxi; };

__device__ inline void combine_min(float& v, int& i, float ov, int oi) {
    if (ov < v || (ov == v && oi < i)) { v = ov; i = oi; }
}
__device__ inline void combine_max(float& v, int& i, float ov, int oi) {
    if (ov > v || (ov == v && oi < i)) { v = ov; i = oi; }
}

__global__ __launch_bounds__(kThr)
void qm_partial(const float* __restrict__ index, float4* __restrict__ ws) {
    const int tid = threadIdx.x;
    const int gid = blockIdx.x * kThr + tid;

    float4 v = reinterpret_cast<const float4*>(index)[gid];
    const int b = 4 * gid;
    float mnv = v.x; int mni = b;
    float mxv = v.x; int mxi = b;
    if (v.y < mnv) { mnv = v.y; mni = b + 1; }
    if (v.y > mxv) { mxv = v.y; mxi = b + 1; }
    if (v.z < mnv) { mnv = v.z; mni = b + 2; }
    if (v.z > mxv) { mxv = v.z; mxi = b + 2; }
    if (v.w < mnv) { mnv = v.w; mni = b + 3; }
    if (v.w > mxv) { mxv = v.w; mxi = b + 3; }

    // wave-64 butterfly: every lane converges to the wave result
    #pragma unroll
    for (int s = 1; s < 64; s <<= 1) {
        float onv = __shfl_xor(mnv, s);
        int   oni = __shfl_xor(mni, s);
        float oxv = __shfl_xor(mxv, s);
        int   oxi = __shfl_xor(mxi, s);
        combine_min(mnv, mni, onv, oni);
        combine_max(mxv, mxi, oxv, oxi);
    }

    __shared__ MinMax s_w[kThr / 64];
    if ((tid & 63) == 0) s_w[tid >> 6] = {mnv, mni, mxv, mxi};
    __syncthreads();
    if (tid == 0) {
        MinMax a = s_w[0];
        #pragma unroll
        for (int i = 1; i < kThr / 64; ++i) {
            combine_min(a.mnv, a.mni, s_w[i].mnv, s_w[i].mni);
            combine_max(a.mxv, a.mxi, s_w[i].mxv, s_w[i].mxi);
        }
        float4 p;
        p.x = a.mnv; p.y = __int_as_float(a.mni);
        p.z = a.mxv; p.w = __int_as_float(a.mxi);
        ws[blockIdx.x] = p;
    }
}

__global__ __launch_bounds__(kThr)
void qm_final(const float* __restrict__ states_seq,  // (1, 128, 512)
              const float* __restrict__ memory,      // (1, 65536, 512)
              const float4* __restrict__ ws,         // 64 partials
              float* __restrict__ out) {              // 513 floats
    __shared__ int   s_m;
    __shared__ float s_maxv;
    __shared__ float s_reward;
    __shared__ float s_rpart[2];
    const int tid = threadIdx.x;

    // waves 1-2: reward column sum (128 strided loads), overlapped with wave 0
    if (tid >= 64 && tid < 192) {
        float x = states_seq[(tid - 64) * kF + (kF - 1)];
        #pragma unroll
        for (int s = 1; s < 64; s <<= 1) x += __shfl_xor(x, s);
        if ((tid & 63) == 0) s_rpart[(tid >> 6) - 1] = x;
    }
    // wave 0: reduce the 64 block partials
    if (tid < 64) {
        float4 p = ws[tid];
        float mnv = p.x; int mni = __float_as_int(p.y);
        float mxv = p.z; int mxi = __float_as_int(p.w);
        #pragma unroll
        for (int s = 1; s < 64; s <<= 1) {
            float onv = __shfl_xor(mnv, s);
            int   oni = __shfl_xor(mni, s);
            float oxv = __shfl_xor(mxv, s);
            int   oxi = __shfl_xor(mxi, s);
            combine_min(mnv, mni, onv, oni);
            combine_max(mxv, mxi, oxv, oxi);
        }
        if (tid == 0) {
            int m = mxi;
            if (mxi == mni) m = (mni == 0) ? 1 : 0;  // all-equal array edge case
            s_m    = m;
            s_maxv = mxv;
        }
    }
    __syncthreads();
    if (tid == 0) s_reward = s_rpart[0] + s_rpart[1];
    __syncthreads();

    const float reward = s_reward;
    const float maxv   = s_maxv;
    const float* src;
    float idxval;
    if (reward > maxv) {
        // appended element wins only on strict > (earlier positions win ties)
        src    = states_seq + (size_t)(kT - 1) * kF;
        idxval = reward;
    } else {
        src    = memory + (size_t)s_m * kF;
        idxval = maxv;  // == index[m]
    }
    const float4* src4 = reinterpret_cast<const float4*>(src);
    float4*       out4 = reinterpret_cast<float4*>(out);
    if (tid < kF / 4) out4[tid] = src4[tid];
    if (tid == 0) out[kF] = idxval;
}

extern "C" void kernel_launch(void* const* d_in, const int* in_sizes, int n_in,
                              void* d_out, int out_size, void* d_ws, size_t ws_size,
                              hipStream_t stream) {
    const float* states_seq = (const float*)d_in[0];
    // d_in[1] = maximum_route: provably unused (cond_s always False).
    const float* memory = (const float*)d_in[2];
    const float* index  = (const float*)d_in[3];
    float*  out = (float*)d_out;
    float4* ws  = (float4*)d_ws;

    qm_partial<<<kBlocks1, kThr, 0, stream>>>(index, ws);
    qm_final<<<1, kThr, 0, stream>>>(states_seq, memory, ws, out);
}